// Round 8
// baseline (918.331 us; speedup 1.0000x reference)
//
#include <hip/hip_runtime.h>
#include <math.h>

#define B_ 32
#define N_ 2048
#define KNN 20
#define FINF 3.402823466e38f
#define SCAP 192

typedef __attribute__((ext_vector_type(8))) short short8;
typedef __attribute__((ext_vector_type(4))) float f32x4;

// ---------------- workspace layout (byte offsets) ----------------
#define OFF_X1   ((size_t)0)                                  // B*N*64 f32
#define OFF_X2   (OFF_X1 + (size_t)B_*N_*64*4)                // B*N*64 f32
#define OFF_SQ1  (OFF_X2 + (size_t)B_*N_*64*4)                // B*N f32
#define OFF_IDX1 (OFF_SQ1 + (size_t)B_*N_*4)                  // B*N*20 i32 (5.2MB; dead after k2)
#define OFF_IDX2 (OFF_IDX1 + (size_t)B_*N_*KNN*4)             // B*N*20 i32
#define OFF_PMAX (OFF_IDX2 + (size_t)B_*N_*KNN*4)             // B*16*1024 f32
#define OFF_PSUM (OFF_PMAX + (size_t)B_*16*1024*4)            // B*16*1024 f32
#define OFF_G    (OFF_PSUM + (size_t)B_*16*1024*4)            // B*2048 f32
#define OFF_FG   (OFF_G + (size_t)B_*2048*4)                  // B*128 f32
#define OFF_DIST (OFF_FG + (size_t)B_*128*4)                  // >=4*N*N f32 = 67.1MB (chunk)
// Overlays of the dist region (sequential lifetimes, exactly 67.109MB total):
//   after all k4s: P (16.78M), Q (16.78M)   [k5pre writes, k5b reads]
//   after k5pre:   XHI (16.78M), XLO (16.78M)  [k5b writes; disjoint from P/Q]
#define OFF_P    OFF_DIST
#define OFF_Q    (OFF_P   + (size_t)B_*N_*64*4)
#define OFF_XHI  (OFF_Q   + (size_t)B_*N_*64*4)
#define OFF_XLO  (OFF_XHI + (size_t)B_*N_*128*2)
// W5 hi/lo live in the dead idx1 region (0.52MB of 5.2MB):
#define OFF_WHI  OFF_IDX1
#define OFF_WLO  (OFF_WHI + (size_t)1024*128*2)

__device__ __forceinline__ float lrelu(float x) { return x >= 0.0f ? x : 0.2f * x; }

__device__ __forceinline__ void bf16split(float a, unsigned short& hi, unsigned short& lo) {
    unsigned u = __float_as_uint(a);
    unsigned r16 = (u + 0x7fffu + ((u >> 16) & 1u)) >> 16;
    hi = (unsigned short)r16;
    float l = a - __uint_as_float(r16 << 16);
    unsigned ul = __float_as_uint(l);
    lo = (unsigned short)((ul + 0x7fffu + ((ul >> 16) & 1u)) >> 16);
}

// ---------------- exact slow-path top-20 (fallback; writes global out) ----------------
template<class F>
__device__ __forceinline__ void wave_top20_slow(const float (&v)[32], int lane, int* gout, F idxf) {
    unsigned alive = 0xffffffffu;
    for (int sel = 0; sel < 20; ++sel) {
        float bv = -FINF;
        int bm = 0x7fffffff;
#pragma unroll
        for (int j = 0; j < 32; ++j) {
            bool a = (alive >> j) & 1u;
            bool better = a && (v[j] > bv);
            bv = better ? v[j] : bv;
            bm = better ? idxf(j) : bm;
        }
#pragma unroll
        for (int off = 32; off; off >>= 1) {
            float ov = __shfl_xor(bv, off, 64);
            int   om = __shfl_xor(bm, off, 64);
            bool take = (ov > bv) || (ov == bv && om < bm);
            bv = take ? ov : bv;
            bm = take ? om : bm;
        }
        if (lane == 0) gout[sel] = bm;
#pragma unroll
        for (int j = 0; j < 32; ++j)
            if (idxf(j) == bm) alive &= ~(1u << j);
    }
}

// ---------------- fast exact top-20: prefilter + compact + bitonic; writes global out ----------------
// t_hat = 20th largest of the 64 lane-maxima => >=20 elements >= t_hat and the exact
// top-20 all >= t20 >= t_hat, so survivors contain the exact set.
template<class F>
__device__ __forceinline__ void wave_top20_fast(const float (&v)[32], int lane,
                                                float* sval, int* sidx, int* gout, F idxf) {
    float lm = v[0];
#pragma unroll
    for (int j = 1; j < 32; ++j) lm = fmaxf(lm, v[j]);
    float s = lm;
#pragma unroll
    for (int k = 2; k <= 64; k <<= 1) {
#pragma unroll
        for (int j2 = k >> 1; j2 > 0; j2 >>= 1) {
            float o = __shfl_xor(s, j2, 64);
            bool up = ((lane & k) == 0);
            bool high = ((lane & j2) != 0);
            s = (high == up) ? fmaxf(s, o) : fminf(s, o);
        }
    }
    float that = __shfl(s, 44, 64);   // 20th largest lane-max
    int cnt = 0;
    unsigned long long below = (lane == 63) ? 0xffffffffffffffffull >> 1
                                            : ((1ull << lane) - 1ull);
#pragma unroll
    for (int j = 0; j < 32; ++j) {
        bool p = (v[j] >= that);
        unsigned long long mk = __ballot(p);
        if (p) {
            int slot = cnt + (int)__popcll(mk & below);
            if (slot < SCAP) { sval[slot] = v[j]; sidx[slot] = idxf(j); }
        }
        cnt += (int)__popcll(mk);
    }
    int S = cnt;
    if (S > SCAP) {
        wave_top20_slow(v, lane, gout, idxf);
        return;
    }
    if (S <= 64) {
        bool ok = lane < S;
        float cv = ok ? sval[lane] : -FINF;
        int   cm = ok ? sidx[lane] : 0x7fffffff;
#pragma unroll
        for (int k = 2; k <= 64; k <<= 1) {
#pragma unroll
            for (int j2 = k >> 1; j2 > 0; j2 >>= 1) {
                float ov = __shfl_xor(cv, j2, 64);
                int   om = __shfl_xor(cm, j2, 64);
                bool up = ((lane & k) == 0);
                bool high = ((lane & j2) != 0);
                bool cur_first = (cv > ov) || (cv == ov && cm < om);
                bool take = (high == up) ? cur_first : !cur_first;
                cv = take ? ov : cv;
                cm = take ? om : cm;
            }
        }
        if (lane < 20) gout[lane] = cm;
    } else {
        float cv[3]; int cm[3]; unsigned alive = 0;
#pragma unroll
        for (int r = 0; r < 3; ++r) {
            int i = r * 64 + lane;
            bool ok = i < S;
            float vv = sval[i];
            int   mm = sidx[i];
            cv[r] = ok ? vv : -FINF;
            cm[r] = ok ? mm : 0x7fffffff;
            if (ok) alive |= 1u << r;
        }
        for (int sel = 0; sel < 20; ++sel) {
            float bv = -FINF; int bm = 0x7fffffff;
#pragma unroll
            for (int r = 0; r < 3; ++r) {
                bool a = (alive >> r) & 1u;
                bool better = a && (cv[r] > bv || (cv[r] == bv && cm[r] < bm));
                bv = better ? cv[r] : bv;
                bm = better ? cm[r] : bm;
            }
#pragma unroll
            for (int off = 32; off; off >>= 1) {
                float ov = __shfl_xor(bv, off, 64);
                int   om = __shfl_xor(bm, off, 64);
                bool take = (ov > bv) || (ov == bv && om < bm);
                bv = take ? ov : bv;
                bm = take ? om : bm;
            }
            if (lane == 0) gout[sel] = bm;
#pragma unroll
            for (int r = 0; r < 3; ++r)
                if (cm[r] == bm) alive &= ~(1u << r);
        }
    }
}

// ---------------- K1: kNN on 3-d positions; float4 LDS, 2 rows/wave ----------------
__global__ __launch_bounds__(256) void k1_knn_pos(const float* __restrict__ x,
                                                  int* __restrict__ idx1) {
    __shared__ float4 sP4[N_];            // 32 KB, 1 ds_read_b128 per candidate
    __shared__ float sval[4][SCAP];
    __shared__ int   sidx[4][SCAP];
    int tid = threadIdx.x;
    int wid = tid >> 6, lane = tid & 63;
    int row0 = blockIdx.x * 8 + wid * 2;  // two consecutive rows per wave, same batch
    int b = row0 >> 11, n0 = row0 & 2047;
    const float* xb = x + (size_t)b * N_ * 6;
    for (int m = tid; m < N_; m += 256) {
        float4 f = *(const float4*)(xb + m * 6);
        f.w = 0.0f;
        sP4[m] = f;
    }
    __syncthreads();
    float4 c0 = sP4[n0], c1 = sP4[n0 + 1];
    float sq0 = c0.x*c0.x + c0.y*c0.y + c0.z*c0.z;
    float sq1v = c1.x*c1.x + c1.y*c1.y + c1.z*c1.z;
    float v0[32], v1[32];
#pragma unroll
    for (int j = 0; j < 32; ++j) {
        int m = lane + (j << 6);
        float4 p = sP4[m];
        float sqm = p.x*p.x + p.y*p.y + p.z*p.z;
        float d0 = c0.x*p.x + c0.y*p.y + c0.z*p.z;
        float d1 = c1.x*p.x + c1.y*p.y + c1.z*p.z;
        v0[j] = 2.0f*d0 - sq0 - sqm;
        v1[j] = 2.0f*d1 - sq1v - sqm;
    }
    auto idxf = [lane](int j) { return lane + (j << 6); };
    wave_top20_fast(v0, lane, sval[wid], sidx[wid], idx1 + (size_t)row0 * KNN, idxf);
    wave_top20_fast(v1, lane, sval[wid], sidx[wid], idx1 + (size_t)(row0 + 1) * KNN, idxf);
}

// ---------------- K2: edgeconv1 (W1: 64x6) + sq of x1 ----------------
__global__ __launch_bounds__(256) void k2_conv1(const float* __restrict__ x,
                                                const int* __restrict__ idx1,
                                                const float* __restrict__ W1,
                                                float* __restrict__ x1,
                                                float* __restrict__ sq1) {
    int wid = threadIdx.x >> 6, o = threadIdx.x & 63;
    int row = blockIdx.x * 4 + wid;
    int b = row >> 11, n = row & 2047;
    const float* xb = x + (size_t)b * N_ * 6;
    float w0 = W1[o*6+0], w1 = W1[o*6+1], w2 = W1[o*6+2];
    float w3 = W1[o*6+3], w4 = W1[o*6+4], w5 = W1[o*6+5];
    float cx = xb[n*6+0], cy = xb[n*6+1], cz = xb[n*6+2];
    float base = w3*cx + w4*cy + w5*cz;
    float mx = -FINF;
    for (int k = 0; k < KNN; ++k) {
        int m = idx1[(size_t)row*KNN + k];
        float dx = xb[m*6+0]-cx, dy = xb[m*6+1]-cy, dz = xb[m*6+2]-cz;
        float s = base + w0*dx + w1*dy + w2*dz;
        s = lrelu(s);
        mx = fmaxf(mx, s);
    }
    x1[(size_t)row*64 + o] = mx;
    float sq = mx*mx;
#pragma unroll
    for (int off = 32; off; off >>= 1) sq += __shfl_xor(sq, off, 64);
    if (o == 0) sq1[row] = sq;
}

// ---------------- K3: neg-dist Gram GEMM (symmetric triangle), chunk of batches ----------------
__global__ __launch_bounds__(256) void k3_dist(const float* __restrict__ x1,
                                               const float* __restrict__ sq1,
                                               float* __restrict__ dist, int b0) {
    __shared__ float sA[32][128];
    __shared__ float sB[32][128];
    int t = blockIdx.x;
    int I = (int)((sqrtf(8.0f*t + 1.0f) - 1.0f) * 0.5f);
    while ((I+1)*(I+2)/2 <= t) ++I;
    while (I*(I+1)/2 > t) --I;
    int J = t - I*(I+1)/2;
    int b = b0 + blockIdx.y;
    const float* Xb  = x1  + (size_t)b * N_ * 64;
    const float* sqb = sq1 + (size_t)b * N_;
    float* Db = dist + (size_t)blockIdx.y * N_ * N_;
    int i0 = I*128, j0 = J*128;
    int tid = threadIdx.x;
    float acc[8][8] = {};
    for (int kt = 0; kt < 64; kt += 32) {
#pragma unroll
        for (int l = 0; l < 4; ++l) {
            int v = l*256 + tid;
            int i = v >> 3, cg = (v & 7) << 2;
            float4 fa = *(const float4*)(Xb + (size_t)(i0+i)*64 + kt + cg);
            sA[cg+0][i] = fa.x; sA[cg+1][i] = fa.y; sA[cg+2][i] = fa.z; sA[cg+3][i] = fa.w;
            float4 fb = *(const float4*)(Xb + (size_t)(j0+i)*64 + kt + cg);
            sB[cg+0][i] = fb.x; sB[cg+1][i] = fb.y; sB[cg+2][i] = fb.z; sB[cg+3][i] = fb.w;
        }
        __syncthreads();
        int ti = (tid & 15) * 8, tj = (tid >> 4) * 8;
#pragma unroll 4
        for (int c = 0; c < 32; ++c) {
            float a[8], w[8];
            *(float4*)&a[0] = *(const float4*)&sA[c][ti];
            *(float4*)&a[4] = *(const float4*)&sA[c][ti+4];
            *(float4*)&w[0] = *(const float4*)&sB[c][tj];
            *(float4*)&w[4] = *(const float4*)&sB[c][tj+4];
#pragma unroll
            for (int ii = 0; ii < 8; ++ii)
#pragma unroll
                for (int jj = 0; jj < 8; ++jj)
                    acc[ii][jj] = fmaf(a[ii], w[jj], acc[ii][jj]);
        }
        __syncthreads();
    }
    int ti = (tid & 15) * 8, tj = (tid >> 4) * 8;
    float sqi[8], sqj[8];
#pragma unroll
    for (int ii = 0; ii < 8; ++ii) sqi[ii] = sqb[i0 + ti + ii];
#pragma unroll
    for (int jj = 0; jj < 8; ++jj) sqj[jj] = sqb[j0 + tj + jj];
#pragma unroll
    for (int ii = 0; ii < 8; ++ii) {
        float ov[8];
#pragma unroll
        for (int jj = 0; jj < 8; ++jj) ov[jj] = 2.0f*acc[ii][jj] - sqi[ii] - sqj[jj];
        float4* p = (float4*)(Db + (size_t)(i0+ti+ii)*N_ + j0 + tj);
        p[0] = *(float4*)&ov[0]; p[1] = *(float4*)&ov[4];
    }
    if (I != J) {
#pragma unroll
        for (int jj = 0; jj < 8; ++jj) {
            float ov[8];
#pragma unroll
            for (int ii = 0; ii < 8; ++ii) ov[ii] = 2.0f*acc[ii][jj] - sqi[ii] - sqj[jj];
            float4* p = (float4*)(Db + (size_t)(j0+tj+jj)*N_ + i0 + ti);
            p[0] = *(float4*)&ov[0]; p[1] = *(float4*)&ov[4];
        }
    }
}

// ---------------- K4: top-20 of materialized dist rows (float4 loads) ----------------
__global__ __launch_bounds__(256) void k4_topk(const float* __restrict__ dist,
                                               int* __restrict__ idx2, int b0) {
    __shared__ float sval[4][SCAP];
    __shared__ int   sidx[4][SCAP];
    int wid = threadIdx.x >> 6, lane = threadIdx.x & 63;
    int lrow = blockIdx.x * 4 + wid;
    int lb = lrow >> 11, n = lrow & 2047;
    const float4* Dr4 = (const float4*)(dist + (size_t)lb * N_ * N_ + (size_t)n * N_);
    float v[32];
#pragma unroll
    for (int j4 = 0; j4 < 8; ++j4) {
        float4 f = Dr4[(j4 << 6) + lane];
        v[j4*4+0] = f.x; v[j4*4+1] = f.y; v[j4*4+2] = f.z; v[j4*4+3] = f.w;
    }
    int row = (b0 + lb) * N_ + n;
    wave_top20_fast(v, lane, sval[wid], sidx[wid], idx2 + (size_t)row * KNN,
                    [lane](int j) { return (lane << 2) + ((j >> 2) << 8) + (j & 3); });
}

// ---------------- K5pre: P = x1 @ Wd^T, Q = x1 @ (Wc - Wd)^T  (W2 = [Wd | Wc]) ----------------
__global__ __launch_bounds__(256) void k5pre_pq(const float* __restrict__ x1,
                                                const float* __restrict__ W2,
                                                float* __restrict__ P,
                                                float* __restrict__ Q) {
    int w = threadIdx.x >> 6, o = threadIdx.x & 63;
    float wd[64], wc[64];
    const float* wsrc = W2 + (size_t)o * 128;
#pragma unroll
    for (int j = 0; j < 16; ++j) {
        float4 d = *(const float4*)(wsrc + j*4);
        float4 c = *(const float4*)(wsrc + 64 + j*4);
        wd[j*4+0] = d.x; wd[j*4+1] = d.y; wd[j*4+2] = d.z; wd[j*4+3] = d.w;
        wc[j*4+0] = c.x - d.x; wc[j*4+1] = c.y - d.y; wc[j*4+2] = c.z - d.z; wc[j*4+3] = c.w - d.w;
    }
    int row0 = (blockIdx.x * 4 + w) * 32;
    for (int r = 0; r < 32; ++r) {
        const float* xr = x1 + (size_t)(row0 + r) * 64;
        float p = 0.0f, q = 0.0f;
#pragma unroll
        for (int j = 0; j < 16; ++j) {
            float4 xc = *(const float4*)(xr + j*4);   // wave-uniform
            p = fmaf(wd[j*4+0], xc.x, p); q = fmaf(wc[j*4+0], xc.x, q);
            p = fmaf(wd[j*4+1], xc.y, p); q = fmaf(wc[j*4+1], xc.y, q);
            p = fmaf(wd[j*4+2], xc.z, p); q = fmaf(wc[j*4+2], xc.z, q);
            p = fmaf(wd[j*4+3], xc.w, p); q = fmaf(wc[j*4+3], xc.w, q);
        }
        P[(size_t)(row0 + r) * 64 + o] = p;
        Q[(size_t)(row0 + r) * 64 + o] = q;
    }
}

// ---------------- K5b: x2 = max_k lrelu(P[m_k]+Q[n]); fused bf16 hi/lo split of [x1|x2] ----------------
__global__ __launch_bounds__(256) void k5b_max(const float* __restrict__ P,
                                               const float* __restrict__ Q,
                                               const int* __restrict__ idx2,
                                               const float* __restrict__ x1,
                                               float* __restrict__ x2,
                                               unsigned short* __restrict__ Xhi,
                                               unsigned short* __restrict__ Xlo) {
    int w = threadIdx.x >> 6, lane = threadIdx.x & 63;
    int row = blockIdx.x * 4 + w;
    int b = row >> 11;
    float q = Q[(size_t)row * 64 + lane];
    const int* id = idx2 + (size_t)row * KNN;
    const float* Pb = P + ((size_t)b << 11) * 64;
    int midx[KNN];
#pragma unroll
    for (int k = 0; k < KNN; ++k) midx[k] = id[k];
    float mx = -FINF;
#pragma unroll
    for (int k = 0; k < KNN; ++k) {
        float p = Pb[(size_t)midx[k] * 64 + lane];
        mx = fmaxf(mx, lrelu(p + q));
    }
    x2[(size_t)row * 64 + lane] = mx;
    float x1v = x1[(size_t)row * 64 + lane];
    unsigned short h0, l0, h1, l1;
    bf16split(x1v, h0, l0);
    bf16split(mx,  h1, l1);
    size_t base = (size_t)row * 128 + lane;
    Xhi[base] = h0;      Xlo[base] = l0;
    Xhi[base + 64] = h1; Xlo[base + 64] = l1;
}

// ---------------- K6pre: split W5 into bf16 hi/lo ----------------
__global__ __launch_bounds__(256) void k6pre_wsplit(const float* __restrict__ W5,
                                                    unsigned short* __restrict__ Whi,
                                                    unsigned short* __restrict__ Wlo) {
    int e = blockIdx.x * 256 + threadIdx.x;   // 32768 float4-groups
    int r = e >> 5, c4 = (e & 31) << 2;
    float4 v = *(const float4*)(W5 + (size_t)r*128 + c4);
    float a[4] = {v.x, v.y, v.z, v.w};
    unsigned short hh[4], ll[4];
#pragma unroll
    for (int i = 0; i < 4; ++i) bf16split(a[i], hh[i], ll[i]);
    size_t doff = (size_t)r*128 + c4;
    *(uint2*)(Whi + doff) = make_uint2((unsigned)hh[0] | ((unsigned)hh[1] << 16),
                                       (unsigned)hh[2] | ((unsigned)hh[3] << 16));
    *(uint2*)(Wlo + doff) = make_uint2((unsigned)ll[0] | ((unsigned)ll[1] << 16),
                                       (unsigned)ll[2] | ((unsigned)ll[3] << 16));
}

// ---------------- K6a (MFMA): h = lrelu(X @ W5^T) split-bf16, fused max/sum pool ----------------
__global__ __launch_bounds__(256) void k6a_mfma(const unsigned short* __restrict__ Xhi,
                                                const unsigned short* __restrict__ Xlo,
                                                const unsigned short* __restrict__ Whi,
                                                const unsigned short* __restrict__ Wlo,
                                                float* __restrict__ pmax,
                                                float* __restrict__ psum) {
    __shared__ unsigned short sT[4][128*32];   // Xh, Xl, Wh, Wl (8KB each)
    __shared__ float redmx[128][2], redsm[128][2];
    int tid = threadIdx.x;
    int nt = blockIdx.x >> 3, ot = blockIdx.x & 7, b = blockIdx.y;
    int wid = tid >> 6, lane = tid & 63;
    int wn = wid & 1, wo = wid >> 1;
    int sub = lane & 15, quad = lane >> 4;
    const unsigned short* gp[4];
    gp[0] = Xhi + (size_t)(b*2048 + nt*128) * 128;
    gp[1] = Xlo + (size_t)(b*2048 + nt*128) * 128;
    gp[2] = Whi + (size_t)(ot*128) * 128;
    gp[3] = Wlo + (size_t)(ot*128) * 128;
    f32x4 acc[4][4];
#pragma unroll
    for (int i = 0; i < 4; ++i)
#pragma unroll
        for (int j = 0; j < 4; ++j) acc[i][j] = (f32x4)0.0f;
    for (int kt = 0; kt < 4; ++kt) {
        int k0 = kt * 32;
        __syncthreads();
#pragma unroll
        for (int it = 0; it < 8; ++it) {
            int task = it*256 + tid;
            int tile = task >> 9, rem = task & 511;
            int row = rem >> 2, ch = rem & 3;
            uint4 d = *(const uint4*)(gp[tile] + (size_t)row*128 + k0 + ch*8);
            *(uint4*)(&sT[tile][row*32 + ch*8]) = d;
        }
        __syncthreads();
        short8 ah[4], al[4], bh[4], bl[4];
#pragma unroll
        for (int mi = 0; mi < 4; ++mi) {
            int r = wn*64 + mi*16 + sub;
            ah[mi] = *(const short8*)(&sT[0][r*32 + quad*8]);
            al[mi] = *(const short8*)(&sT[1][r*32 + quad*8]);
        }
#pragma unroll
        for (int ni = 0; ni < 4; ++ni) {
            int r = wo*64 + ni*16 + sub;
            bh[ni] = *(const short8*)(&sT[2][r*32 + quad*8]);
            bl[ni] = *(const short8*)(&sT[3][r*32 + quad*8]);
        }
#pragma unroll
        for (int mi = 0; mi < 4; ++mi)
#pragma unroll
            for (int ni = 0; ni < 4; ++ni) {
                acc[mi][ni] = __builtin_amdgcn_mfma_f32_16x16x32_bf16(ah[mi], bh[ni], acc[mi][ni], 0, 0, 0);
                acc[mi][ni] = __builtin_amdgcn_mfma_f32_16x16x32_bf16(ah[mi], bl[ni], acc[mi][ni], 0, 0, 0);
                acc[mi][ni] = __builtin_amdgcn_mfma_f32_16x16x32_bf16(al[mi], bh[ni], acc[mi][ni], 0, 0, 0);
            }
    }
#pragma unroll
    for (int ni = 0; ni < 4; ++ni) {
        float mx = -FINF, sm = 0.0f;
#pragma unroll
        for (int mi = 0; mi < 4; ++mi)
#pragma unroll
            for (int r = 0; r < 4; ++r) {
                float v = lrelu(acc[mi][ni][r]);
                mx = fmaxf(mx, v); sm += v;
            }
        mx = fmaxf(mx, __shfl_xor(mx, 16, 64));
        mx = fmaxf(mx, __shfl_xor(mx, 32, 64));
        sm += __shfl_xor(sm, 16, 64);
        sm += __shfl_xor(sm, 32, 64);
        if (quad == 0) {
            redmx[wo*64 + ni*16 + sub][wn] = mx;
            redsm[wo*64 + ni*16 + sub][wn] = sm;
        }
    }
    __syncthreads();
    if (tid < 128) {
        float mx = fmaxf(redmx[tid][0], redmx[tid][1]);
        float sm = redsm[tid][0] + redsm[tid][1];
        size_t po = ((size_t)b*16 + nt)*1024 + ot*128 + tid;
        pmax[po] = mx; psum[po] = sm;
    }
}

// ---------------- K6b: reduce 16 n-tiles -> g = [max(1024), mean(1024)] ----------------
__global__ __launch_bounds__(256) void k6b_reduce(const float* __restrict__ pmax,
                                                  const float* __restrict__ psum,
                                                  float* __restrict__ g) {
    int t = blockIdx.x * 256 + threadIdx.x;
    int b = t >> 10, o = t & 1023;
    float mx = -FINF, sm = 0.0f;
    for (int i = 0; i < 16; ++i) {
        mx = fmaxf(mx, pmax[((size_t)b*16 + i)*1024 + o]);
        sm += psum[((size_t)b*16 + i)*1024 + o];
    }
    g[(size_t)b*2048 + o] = mx;
    g[(size_t)b*2048 + 1024 + o] = sm * (1.0f/2048.0f);
}

// ---------------- K7: feature branch (W3:32x3, W4:64x32) + pool -> fg(B,128) ----------------
__global__ __launch_bounds__(256) void k7_feat(const float* __restrict__ x,
                                               const float* __restrict__ W3,
                                               const float* __restrict__ W4,
                                               float* __restrict__ fg) {
    __shared__ float rmx[16*256];
    __shared__ float rsm[16*256];
    int b = blockIdx.y, og = blockIdx.x;
    int o0 = og * 16;
    int tid = threadIdx.x;
    float mx[16], sm[16];
#pragma unroll
    for (int i = 0; i < 16; ++i) { mx[i] = -FINF; sm[i] = 0.0f; }
    for (int n = tid; n < N_; n += 256) {
        const float* xr = x + ((size_t)b*N_ + n)*6 + 3;
        float f0 = xr[0], f1 = xr[1], f2 = xr[2];
        float h1[32];
#pragma unroll
        for (int j = 0; j < 32; ++j) {
            float s = W3[j*3]*f0 + W3[j*3+1]*f1 + W3[j*3+2]*f2;
            h1[j] = lrelu(s);
        }
#pragma unroll
        for (int oi = 0; oi < 16; ++oi) {
            float s = 0.0f;
#pragma unroll
            for (int j = 0; j < 32; ++j) s = fmaf(W4[(o0+oi)*32 + j], h1[j], s);
            s = lrelu(s);
            mx[oi] = fmaxf(mx[oi], s); sm[oi] += s;
        }
    }
#pragma unroll
    for (int oi = 0; oi < 16; ++oi) { rmx[oi*256 + tid] = mx[oi]; rsm[oi*256 + tid] = sm[oi]; }
    __syncthreads();
    for (int s = 128; s > 0; s >>= 1) {
        if (tid < s) {
#pragma unroll
            for (int oi = 0; oi < 16; ++oi) {
                rmx[oi*256 + tid] = fmaxf(rmx[oi*256 + tid], rmx[oi*256 + tid + s]);
                rsm[oi*256 + tid] += rsm[oi*256 + tid + s];
            }
        }
        __syncthreads();
    }
    if (tid < 16) {
        fg[(size_t)b*128 + o0 + tid]      = rmx[tid*256];
        fg[(size_t)b*128 + 64 + o0 + tid] = rsm[tid*256] * (1.0f/2048.0f);
    }
}

// ---------------- K8: head MLP 2176 -> 128 -> 64 -> 40 ----------------
__global__ __launch_bounds__(128) void k8_head(const float* __restrict__ g,
                                               const float* __restrict__ fg,
                                               const float* __restrict__ L1w,
                                               const float* __restrict__ L2w,
                                               const float* __restrict__ L2b,
                                               const float* __restrict__ L3w,
                                               const float* __restrict__ L3b,
                                               float* __restrict__ out) {
    __shared__ float sz[2176];
    __shared__ float s1[128];
    __shared__ float s2[64];
    int b = blockIdx.x, tid = threadIdx.x;
    for (int c = tid; c < 2048; c += 128) sz[c] = g[(size_t)b*2048 + c];
    if (tid < 128) sz[2048 + tid] = fg[(size_t)b*128 + tid];
    __syncthreads();
    {
        float a = 0.0f;
        const float* w = L1w + (size_t)tid * 2176;
        for (int c = 0; c < 2176; ++c) a = fmaf(w[c], sz[c], a);
        s1[tid] = lrelu(a);
    }
    __syncthreads();
    if (tid < 64) {
        float a = L2b[tid];
        for (int c = 0; c < 128; ++c) a = fmaf(L2w[tid*128 + c], s1[c], a);
        s2[tid] = lrelu(a);
    }
    __syncthreads();
    if (tid < 40) {
        float a = L3b[tid];
        for (int c = 0; c < 64; ++c) a = fmaf(L3w[tid*64 + c], s2[c], a);
        out[(size_t)b*40 + tid] = a;
    }
}

// ---------------- launcher ----------------
extern "C" void kernel_launch(void* const* d_in, const int* in_sizes, int n_in,
                              void* d_out, int out_size, void* d_ws, size_t ws_size,
                              hipStream_t stream) {
    const float* x   = (const float*)d_in[0];
    const float* W1  = (const float*)d_in[1];
    const float* W2  = (const float*)d_in[2];
    const float* W5  = (const float*)d_in[3];
    const float* W3  = (const float*)d_in[4];
    const float* W4  = (const float*)d_in[5];
    const float* L1w = (const float*)d_in[6];
    const float* L2w = (const float*)d_in[7];
    const float* L2b = (const float*)d_in[8];
    const float* L3w = (const float*)d_in[9];
    const float* L3b = (const float*)d_in[10];
    float* out = (float*)d_out;

    char* ws = (char*)d_ws;
    float* x1   = (float*)(ws + OFF_X1);
    float* x2   = (float*)(ws + OFF_X2);
    float* sq1  = (float*)(ws + OFF_SQ1);
    int*   idx1 = (int*)  (ws + OFF_IDX1);
    int*   idx2 = (int*)  (ws + OFF_IDX2);
    float* pmax = (float*)(ws + OFF_PMAX);
    float* psum = (float*)(ws + OFF_PSUM);
    float* g    = (float*)(ws + OFF_G);
    float* fg   = (float*)(ws + OFF_FG);
    float* dist = (float*)(ws + OFF_DIST);
    float* P    = (float*)(ws + OFF_P);
    float* Q    = (float*)(ws + OFF_Q);
    unsigned short* Xhi = (unsigned short*)(ws + OFF_XHI);
    unsigned short* Xlo = (unsigned short*)(ws + OFF_XLO);
    unsigned short* Whi = (unsigned short*)(ws + OFF_WHI);
    unsigned short* Wlo = (unsigned short*)(ws + OFF_WLO);

    size_t distBytes = (size_t)N_ * N_ * 4;
    size_t availB = (ws_size > OFF_DIST) ? (ws_size - OFF_DIST) : 0;
    int maxcb = (int)(availB / distBytes);
    int cb = 4;
    while (cb * 2 <= maxcb && cb * 2 <= 32) cb <<= 1;

    k1_knn_pos<<<8192, 256, 0, stream>>>(x, idx1);
    k2_conv1<<<16384, 256, 0, stream>>>(x, idx1, W1, x1, sq1);
    for (int b0 = 0; b0 < 32; b0 += cb) {
        k3_dist<<<dim3(136, cb), 256, 0, stream>>>(x1, sq1, dist, b0);
        k4_topk<<<cb * 512, 256, 0, stream>>>(dist, idx2, b0);
    }
    k5pre_pq<<<512, 256, 0, stream>>>(x1, W2, P, Q);
    k5b_max<<<16384, 256, 0, stream>>>(P, Q, idx2, x1, x2, Xhi, Xlo);
    k6pre_wsplit<<<128, 256, 0, stream>>>(W5, Whi, Wlo);
    k6a_mfma<<<dim3(128, 32), 256, 0, stream>>>(Xhi, Xlo, Whi, Wlo, pmax, psum);
    k6b_reduce<<<128, 256, 0, stream>>>(pmax, psum, g);
    k7_feat<<<dim3(4, 32), 256, 0, stream>>>(x, W3, W4, fg);
    k8_head<<<32, 128, 0, stream>>>(g, fg, L1w, L2w, L2b, L3w, L3b, out);
}

// Round 9
// 848.357 us; speedup vs baseline: 1.0825x; 1.0825x over previous
//
#include <hip/hip_runtime.h>
#include <math.h>

#define B_ 32
#define N_ 2048
#define KNN 20
#define FINF 3.402823466e38f
#define SCAP 192

typedef __attribute__((ext_vector_type(8))) short short8;
typedef __attribute__((ext_vector_type(4))) float f32x4;

// ---------------- workspace layout (byte offsets) ----------------
#define OFF_X1   ((size_t)0)                                  // B*N*64 f32
#define OFF_X2   (OFF_X1 + (size_t)B_*N_*64*4)                // B*N*64 f32
#define OFF_SQ1  (OFF_X2 + (size_t)B_*N_*64*4)                // B*N f32
#define OFF_IDX1 (OFF_SQ1 + (size_t)B_*N_*4)                  // B*N*20 i32 (5.2MB; dead after k2)
#define OFF_IDX2 (OFF_IDX1 + (size_t)B_*N_*KNN*4)             // B*N*20 i32
#define OFF_PMAX (OFF_IDX2 + (size_t)B_*N_*KNN*4)             // B*16*1024 f32
#define OFF_PSUM (OFF_PMAX + (size_t)B_*16*1024*4)            // B*16*1024 f32
#define OFF_G    (OFF_PSUM + (size_t)B_*16*1024*4)            // B*2048 f32
#define OFF_FG   (OFF_G + (size_t)B_*2048*4)                  // B*128 f32
#define OFF_DIST (OFF_FG + (size_t)B_*128*4)                  // >=4*N*N f32 = 67.1MB (chunk)
// Overlays of the dist region (sequential lifetimes):
//   after all k4s: P (16.78M), Q (16.78M)   [k5pre writes, k5b reads]
//   after k5pre:   XHI (16.78M), XLO (16.78M)  [k5b writes; disjoint from P/Q]
#define OFF_P    OFF_DIST
#define OFF_Q    (OFF_P   + (size_t)B_*N_*64*4)
#define OFF_XHI  (OFF_Q   + (size_t)B_*N_*64*4)
#define OFF_XLO  (OFF_XHI + (size_t)B_*N_*128*2)
// W5 hi/lo live in the dead idx1 region (0.52MB of 5.2MB):
#define OFF_WHI  OFF_IDX1
#define OFF_WLO  (OFF_WHI + (size_t)1024*128*2)

__device__ __forceinline__ float lrelu(float x) { return x >= 0.0f ? x : 0.2f * x; }

__device__ __forceinline__ void bf16split(float a, unsigned short& hi, unsigned short& lo) {
    unsigned u = __float_as_uint(a);
    unsigned r16 = (u + 0x7fffu + ((u >> 16) & 1u)) >> 16;
    hi = (unsigned short)r16;
    float l = a - __uint_as_float(r16 << 16);
    unsigned ul = __float_as_uint(l);
    lo = (unsigned short)((ul + 0x7fffu + ((ul >> 16) & 1u)) >> 16);
}

// ---------------- exact slow-path top-20 (fallback; writes global out) ----------------
template<class F>
__device__ __forceinline__ void wave_top20_slow(const float (&v)[32], int lane, int* gout, F idxf) {
    unsigned alive = 0xffffffffu;
    for (int sel = 0; sel < 20; ++sel) {
        float bv = -FINF;
        int bm = 0x7fffffff;
#pragma unroll
        for (int j = 0; j < 32; ++j) {
            bool a = (alive >> j) & 1u;
            bool better = a && (v[j] > bv);
            bv = better ? v[j] : bv;
            bm = better ? idxf(j) : bm;
        }
#pragma unroll
        for (int off = 32; off; off >>= 1) {
            float ov = __shfl_xor(bv, off, 64);
            int   om = __shfl_xor(bm, off, 64);
            bool take = (ov > bv) || (ov == bv && om < bm);
            bv = take ? ov : bv;
            bm = take ? om : bm;
        }
        if (lane == 0) gout[sel] = bm;
#pragma unroll
        for (int j = 0; j < 32; ++j)
            if (idxf(j) == bm) alive &= ~(1u << j);
    }
}

// ---------------- fast exact top-20: prefilter + compact + bitonic; writes global out ----------------
// t_hat = 20th largest of the 64 lane-maxima => >=20 elements >= t_hat and the exact
// top-20 all >= t20 >= t_hat, so survivors contain the exact set.
template<class F>
__device__ __forceinline__ void wave_top20_fast(const float (&v)[32], int lane,
                                                float* sval, int* sidx, int* gout, F idxf) {
    float lm = v[0];
#pragma unroll
    for (int j = 1; j < 32; ++j) lm = fmaxf(lm, v[j]);
    float s = lm;
#pragma unroll
    for (int k = 2; k <= 64; k <<= 1) {
#pragma unroll
        for (int j2 = k >> 1; j2 > 0; j2 >>= 1) {
            float o = __shfl_xor(s, j2, 64);
            bool up = ((lane & k) == 0);
            bool high = ((lane & j2) != 0);
            s = (high == up) ? fmaxf(s, o) : fminf(s, o);
        }
    }
    float that = __shfl(s, 44, 64);   // 20th largest lane-max
    int cnt = 0;
    unsigned long long below = (lane == 63) ? 0xffffffffffffffffull >> 1
                                            : ((1ull << lane) - 1ull);
#pragma unroll
    for (int j = 0; j < 32; ++j) {
        bool p = (v[j] >= that);
        unsigned long long mk = __ballot(p);
        if (p) {
            int slot = cnt + (int)__popcll(mk & below);
            if (slot < SCAP) { sval[slot] = v[j]; sidx[slot] = idxf(j); }
        }
        cnt += (int)__popcll(mk);
    }
    int S = cnt;
    if (S > SCAP) {
        wave_top20_slow(v, lane, gout, idxf);
        return;
    }
    if (S <= 64) {
        bool ok = lane < S;
        float cv = ok ? sval[lane] : -FINF;
        int   cm = ok ? sidx[lane] : 0x7fffffff;
#pragma unroll
        for (int k = 2; k <= 64; k <<= 1) {
#pragma unroll
            for (int j2 = k >> 1; j2 > 0; j2 >>= 1) {
                float ov = __shfl_xor(cv, j2, 64);
                int   om = __shfl_xor(cm, j2, 64);
                bool up = ((lane & k) == 0);
                bool high = ((lane & j2) != 0);
                bool cur_first = (cv > ov) || (cv == ov && cm < om);
                bool take = (high == up) ? cur_first : !cur_first;
                cv = take ? ov : cv;
                cm = take ? om : cm;
            }
        }
        if (lane < 20) gout[lane] = cm;
    } else {
        float cv[3]; int cm[3]; unsigned alive = 0;
#pragma unroll
        for (int r = 0; r < 3; ++r) {
            int i = r * 64 + lane;
            bool ok = i < S;
            float vv = sval[i];
            int   mm = sidx[i];
            cv[r] = ok ? vv : -FINF;
            cm[r] = ok ? mm : 0x7fffffff;
            if (ok) alive |= 1u << r;
        }
        for (int sel = 0; sel < 20; ++sel) {
            float bv = -FINF; int bm = 0x7fffffff;
#pragma unroll
            for (int r = 0; r < 3; ++r) {
                bool a = (alive >> r) & 1u;
                bool better = a && (cv[r] > bv || (cv[r] == bv && cm[r] < bm));
                bv = better ? cv[r] : bv;
                bm = better ? cm[r] : bm;
            }
#pragma unroll
            for (int off = 32; off; off >>= 1) {
                float ov = __shfl_xor(bv, off, 64);
                int   om = __shfl_xor(bm, off, 64);
                bool take = (ov > bv) || (ov == bv && om < bm);
                bv = take ? ov : bv;
                bm = take ? om : bm;
            }
            if (lane == 0) gout[sel] = bm;
#pragma unroll
            for (int r = 0; r < 3; ++r)
                if (cm[r] == bm) alive &= ~(1u << r);
        }
    }
}

// ---------------- K1: kNN on 3-d positions (R7 structure: 1 row/wave, scalar LDS) ----------------
// sP stride 3 floats/candidate: bank = (3m+c)%32, 64 lanes -> 2 lanes/bank = free.
__global__ __launch_bounds__(256) void k1_knn_pos(const float* __restrict__ x,
                                                  int* __restrict__ idx1) {
    __shared__ float sP[N_ * 3];          // 24 KB
    __shared__ float sval[4][SCAP];
    __shared__ int   sidx[4][SCAP];
    int tid = threadIdx.x;
    int wid = tid >> 6, lane = tid & 63;
    int row = blockIdx.x * 4 + wid;
    int b = row >> 11, n = row & 2047;
    const float* xb = x + (size_t)b * N_ * 6;
    for (int m = tid; m < N_; m += 256) {
        float4 f = *(const float4*)(xb + m * 6);
        sP[m*3+0] = f.x; sP[m*3+1] = f.y; sP[m*3+2] = f.z;
    }
    __syncthreads();
    float cx = sP[n*3+0], cy = sP[n*3+1], cz = sP[n*3+2];
    float sqn = cx*cx + cy*cy + cz*cz;
    float v[32];
#pragma unroll
    for (int j = 0; j < 32; ++j) {
        int m = lane + (j << 6);
        float mx_ = sP[m*3+0], my = sP[m*3+1], mz = sP[m*3+2];
        float inner = cx*mx_ + cy*my + cz*mz;
        float sqm = mx_*mx_ + my*my + mz*mz;
        v[j] = 2.0f*inner - sqn - sqm;
    }
    wave_top20_fast(v, lane, sval[wid], sidx[wid], idx1 + (size_t)row * KNN,
                    [lane](int j) { return lane + (j << 6); });
}

// ---------------- K2: edgeconv1 (W1: 64x6) + sq of x1 ----------------
__global__ __launch_bounds__(256) void k2_conv1(const float* __restrict__ x,
                                                const int* __restrict__ idx1,
                                                const float* __restrict__ W1,
                                                float* __restrict__ x1,
                                                float* __restrict__ sq1) {
    int wid = threadIdx.x >> 6, o = threadIdx.x & 63;
    int row = blockIdx.x * 4 + wid;
    int b = row >> 11, n = row & 2047;
    const float* xb = x + (size_t)b * N_ * 6;
    float w0 = W1[o*6+0], w1 = W1[o*6+1], w2 = W1[o*6+2];
    float w3 = W1[o*6+3], w4 = W1[o*6+4], w5 = W1[o*6+5];
    float cx = xb[n*6+0], cy = xb[n*6+1], cz = xb[n*6+2];
    float base = w3*cx + w4*cy + w5*cz;
    float mx = -FINF;
    for (int k = 0; k < KNN; ++k) {
        int m = idx1[(size_t)row*KNN + k];
        float dx = xb[m*6+0]-cx, dy = xb[m*6+1]-cy, dz = xb[m*6+2]-cz;
        float s = base + w0*dx + w1*dy + w2*dz;
        s = lrelu(s);
        mx = fmaxf(mx, s);
    }
    x1[(size_t)row*64 + o] = mx;
    float sq = mx*mx;
#pragma unroll
    for (int off = 32; off; off >>= 1) sq += __shfl_xor(sq, off, 64);
    if (o == 0) sq1[row] = sq;
}

// ---------------- K3: neg-dist Gram GEMM (symmetric triangle), chunk of batches ----------------
__global__ __launch_bounds__(256) void k3_dist(const float* __restrict__ x1,
                                               const float* __restrict__ sq1,
                                               float* __restrict__ dist, int b0) {
    __shared__ float sA[32][128];
    __shared__ float sB[32][128];
    int t = blockIdx.x;
    int I = (int)((sqrtf(8.0f*t + 1.0f) - 1.0f) * 0.5f);
    while ((I+1)*(I+2)/2 <= t) ++I;
    while (I*(I+1)/2 > t) --I;
    int J = t - I*(I+1)/2;
    int b = b0 + blockIdx.y;
    const float* Xb  = x1  + (size_t)b * N_ * 64;
    const float* sqb = sq1 + (size_t)b * N_;
    float* Db = dist + (size_t)blockIdx.y * N_ * N_;
    int i0 = I*128, j0 = J*128;
    int tid = threadIdx.x;
    float acc[8][8] = {};
    for (int kt = 0; kt < 64; kt += 32) {
#pragma unroll
        for (int l = 0; l < 4; ++l) {
            int v = l*256 + tid;
            int i = v >> 3, cg = (v & 7) << 2;
            float4 fa = *(const float4*)(Xb + (size_t)(i0+i)*64 + kt + cg);
            sA[cg+0][i] = fa.x; sA[cg+1][i] = fa.y; sA[cg+2][i] = fa.z; sA[cg+3][i] = fa.w;
            float4 fb = *(const float4*)(Xb + (size_t)(j0+i)*64 + kt + cg);
            sB[cg+0][i] = fb.x; sB[cg+1][i] = fb.y; sB[cg+2][i] = fb.z; sB[cg+3][i] = fb.w;
        }
        __syncthreads();
        int ti = (tid & 15) * 8, tj = (tid >> 4) * 8;
#pragma unroll 4
        for (int c = 0; c < 32; ++c) {
            float a[8], w[8];
            *(float4*)&a[0] = *(const float4*)&sA[c][ti];
            *(float4*)&a[4] = *(const float4*)&sA[c][ti+4];
            *(float4*)&w[0] = *(const float4*)&sB[c][tj];
            *(float4*)&w[4] = *(const float4*)&sB[c][tj+4];
#pragma unroll
            for (int ii = 0; ii < 8; ++ii)
#pragma unroll
                for (int jj = 0; jj < 8; ++jj)
                    acc[ii][jj] = fmaf(a[ii], w[jj], acc[ii][jj]);
        }
        __syncthreads();
    }
    int ti = (tid & 15) * 8, tj = (tid >> 4) * 8;
    float sqi[8], sqj[8];
#pragma unroll
    for (int ii = 0; ii < 8; ++ii) sqi[ii] = sqb[i0 + ti + ii];
#pragma unroll
    for (int jj = 0; jj < 8; ++jj) sqj[jj] = sqb[j0 + tj + jj];
#pragma unroll
    for (int ii = 0; ii < 8; ++ii) {
        float ov[8];
#pragma unroll
        for (int jj = 0; jj < 8; ++jj) ov[jj] = 2.0f*acc[ii][jj] - sqi[ii] - sqj[jj];
        float4* p = (float4*)(Db + (size_t)(i0+ti+ii)*N_ + j0 + tj);
        p[0] = *(float4*)&ov[0]; p[1] = *(float4*)&ov[4];
    }
    if (I != J) {
#pragma unroll
        for (int jj = 0; jj < 8; ++jj) {
            float ov[8];
#pragma unroll
            for (int ii = 0; ii < 8; ++ii) ov[ii] = 2.0f*acc[ii][jj] - sqi[ii] - sqj[jj];
            float4* p = (float4*)(Db + (size_t)(j0+tj+jj)*N_ + i0 + ti);
            p[0] = *(float4*)&ov[0]; p[1] = *(float4*)&ov[4];
        }
    }
}

// ---------------- K4: top-20 of materialized dist rows (float4 loads) ----------------
__global__ __launch_bounds__(256) void k4_topk(const float* __restrict__ dist,
                                               int* __restrict__ idx2, int b0) {
    __shared__ float sval[4][SCAP];
    __shared__ int   sidx[4][SCAP];
    int wid = threadIdx.x >> 6, lane = threadIdx.x & 63;
    int lrow = blockIdx.x * 4 + wid;
    int lb = lrow >> 11, n = lrow & 2047;
    const float4* Dr4 = (const float4*)(dist + (size_t)lb * N_ * N_ + (size_t)n * N_);
    float v[32];
#pragma unroll
    for (int j4 = 0; j4 < 8; ++j4) {
        float4 f = Dr4[(j4 << 6) + lane];
        v[j4*4+0] = f.x; v[j4*4+1] = f.y; v[j4*4+2] = f.z; v[j4*4+3] = f.w;
    }
    int row = (b0 + lb) * N_ + n;
    wave_top20_fast(v, lane, sval[wid], sidx[wid], idx2 + (size_t)row * KNN,
                    [lane](int j) { return (lane << 2) + ((j >> 2) << 8) + (j & 3); });
}

// ---------------- K5pre: P = x1 @ Wd^T, Q = x1 @ (Wc-Wd)^T; blocks >=512 split W5 ----------------
__global__ __launch_bounds__(256) void k5pre_pq(const float* __restrict__ x1,
                                                const float* __restrict__ W2,
                                                float* __restrict__ P,
                                                float* __restrict__ Q,
                                                const float* __restrict__ W5,
                                                unsigned short* __restrict__ Whi,
                                                unsigned short* __restrict__ Wlo) {
    if (blockIdx.x >= 512) {
        // W5 split: 32768 float4-groups over 128 blocks
        int e = (blockIdx.x - 512) * 256 + threadIdx.x;
        int r = e >> 5, c4 = (e & 31) << 2;
        float4 v = *(const float4*)(W5 + (size_t)r*128 + c4);
        float a[4] = {v.x, v.y, v.z, v.w};
        unsigned short hh[4], ll[4];
#pragma unroll
        for (int i = 0; i < 4; ++i) bf16split(a[i], hh[i], ll[i]);
        size_t doff = (size_t)r*128 + c4;
        *(uint2*)(Whi + doff) = make_uint2((unsigned)hh[0] | ((unsigned)hh[1] << 16),
                                           (unsigned)hh[2] | ((unsigned)hh[3] << 16));
        *(uint2*)(Wlo + doff) = make_uint2((unsigned)ll[0] | ((unsigned)ll[1] << 16),
                                           (unsigned)ll[2] | ((unsigned)ll[3] << 16));
        return;
    }
    int w = threadIdx.x >> 6, o = threadIdx.x & 63;
    float wd[64], wc[64];
    const float* wsrc = W2 + (size_t)o * 128;
#pragma unroll
    for (int j = 0; j < 16; ++j) {
        float4 d = *(const float4*)(wsrc + j*4);
        float4 c = *(const float4*)(wsrc + 64 + j*4);
        wd[j*4+0] = d.x; wd[j*4+1] = d.y; wd[j*4+2] = d.z; wd[j*4+3] = d.w;
        wc[j*4+0] = c.x - d.x; wc[j*4+1] = c.y - d.y; wc[j*4+2] = c.z - d.z; wc[j*4+3] = c.w - d.w;
    }
    int row0 = (blockIdx.x * 4 + w) * 32;
    for (int r = 0; r < 32; ++r) {
        const float* xr = x1 + (size_t)(row0 + r) * 64;
        float p = 0.0f, q = 0.0f;
#pragma unroll
        for (int j = 0; j < 16; ++j) {
            float4 xc = *(const float4*)(xr + j*4);   // wave-uniform
            p = fmaf(wd[j*4+0], xc.x, p); q = fmaf(wc[j*4+0], xc.x, q);
            p = fmaf(wd[j*4+1], xc.y, p); q = fmaf(wc[j*4+1], xc.y, q);
            p = fmaf(wd[j*4+2], xc.z, p); q = fmaf(wc[j*4+2], xc.z, q);
            p = fmaf(wd[j*4+3], xc.w, p); q = fmaf(wc[j*4+3], xc.w, q);
        }
        P[(size_t)(row0 + r) * 64 + o] = p;
        Q[(size_t)(row0 + r) * 64 + o] = q;
    }
}

// ---------------- K5b: x2 = max_k lrelu(P[m_k]+Q[n]); fused bf16 hi/lo split of [x1|x2] ----------------
__global__ __launch_bounds__(256) void k5b_max(const float* __restrict__ P,
                                               const float* __restrict__ Q,
                                               const int* __restrict__ idx2,
                                               const float* __restrict__ x1,
                                               float* __restrict__ x2,
                                               unsigned short* __restrict__ Xhi,
                                               unsigned short* __restrict__ Xlo) {
    int w = threadIdx.x >> 6, lane = threadIdx.x & 63;
    int row = blockIdx.x * 4 + w;
    int b = row >> 11;
    float q = Q[(size_t)row * 64 + lane];
    const int* id = idx2 + (size_t)row * KNN;
    const float* Pb = P + ((size_t)b << 11) * 64;
    int midx[KNN];
#pragma unroll
    for (int k = 0; k < KNN; ++k) midx[k] = id[k];
    float mx = -FINF;
#pragma unroll
    for (int k = 0; k < KNN; ++k) {
        float p = Pb[(size_t)midx[k] * 64 + lane];
        mx = fmaxf(mx, lrelu(p + q));
    }
    x2[(size_t)row * 64 + lane] = mx;
    float x1v = x1[(size_t)row * 64 + lane];
    unsigned short h0, l0, h1, l1;
    bf16split(x1v, h0, l0);
    bf16split(mx,  h1, l1);
    size_t base = (size_t)row * 128 + lane;
    Xhi[base] = h0;      Xlo[base] = l0;
    Xhi[base + 64] = h1; Xlo[base + 64] = l1;
}

// ---------------- K6a (MFMA): h = lrelu(X @ W5^T) split-bf16, fused max/sum pool ----------------
__global__ __launch_bounds__(256) void k6a_mfma(const unsigned short* __restrict__ Xhi,
                                                const unsigned short* __restrict__ Xlo,
                                                const unsigned short* __restrict__ Whi,
                                                const unsigned short* __restrict__ Wlo,
                                                float* __restrict__ pmax,
                                                float* __restrict__ psum) {
    __shared__ unsigned short sT[4][128*32];   // Xh, Xl, Wh, Wl (8KB each)
    __shared__ float redmx[128][2], redsm[128][2];
    int tid = threadIdx.x;
    int nt = blockIdx.x >> 3, ot = blockIdx.x & 7, b = blockIdx.y;
    int wid = tid >> 6, lane = tid & 63;
    int wn = wid & 1, wo = wid >> 1;
    int sub = lane & 15, quad = lane >> 4;
    const unsigned short* gp[4];
    gp[0] = Xhi + (size_t)(b*2048 + nt*128) * 128;
    gp[1] = Xlo + (size_t)(b*2048 + nt*128) * 128;
    gp[2] = Whi + (size_t)(ot*128) * 128;
    gp[3] = Wlo + (size_t)(ot*128) * 128;
    f32x4 acc[4][4];
#pragma unroll
    for (int i = 0; i < 4; ++i)
#pragma unroll
        for (int j = 0; j < 4; ++j) acc[i][j] = (f32x4)0.0f;
    for (int kt = 0; kt < 4; ++kt) {
        int k0 = kt * 32;
        __syncthreads();
#pragma unroll
        for (int it = 0; it < 8; ++it) {
            int task = it*256 + tid;
            int tile = task >> 9, rem = task & 511;
            int row = rem >> 2, ch = rem & 3;
            uint4 d = *(const uint4*)(gp[tile] + (size_t)row*128 + k0 + ch*8);
            *(uint4*)(&sT[tile][row*32 + ch*8]) = d;
        }
        __syncthreads();
        short8 ah[4], al[4], bh[4], bl[4];
#pragma unroll
        for (int mi = 0; mi < 4; ++mi) {
            int r = wn*64 + mi*16 + sub;
            ah[mi] = *(const short8*)(&sT[0][r*32 + quad*8]);
            al[mi] = *(const short8*)(&sT[1][r*32 + quad*8]);
        }
#pragma unroll
        for (int ni = 0; ni < 4; ++ni) {
            int r = wo*64 + ni*16 + sub;
            bh[ni] = *(const short8*)(&sT[2][r*32 + quad*8]);
            bl[ni] = *(const short8*)(&sT[3][r*32 + quad*8]);
        }
#pragma unroll
        for (int mi = 0; mi < 4; ++mi)
#pragma unroll
            for (int ni = 0; ni < 4; ++ni) {
                acc[mi][ni] = __builtin_amdgcn_mfma_f32_16x16x32_bf16(ah[mi], bh[ni], acc[mi][ni], 0, 0, 0);
                acc[mi][ni] = __builtin_amdgcn_mfma_f32_16x16x32_bf16(ah[mi], bl[ni], acc[mi][ni], 0, 0, 0);
                acc[mi][ni] = __builtin_amdgcn_mfma_f32_16x16x32_bf16(al[mi], bh[ni], acc[mi][ni], 0, 0, 0);
            }
    }
#pragma unroll
    for (int ni = 0; ni < 4; ++ni) {
        float mx = -FINF, sm = 0.0f;
#pragma unroll
        for (int mi = 0; mi < 4; ++mi)
#pragma unroll
            for (int r = 0; r < 4; ++r) {
                float v = lrelu(acc[mi][ni][r]);
                mx = fmaxf(mx, v); sm += v;
            }
        mx = fmaxf(mx, __shfl_xor(mx, 16, 64));
        mx = fmaxf(mx, __shfl_xor(mx, 32, 64));
        sm += __shfl_xor(sm, 16, 64);
        sm += __shfl_xor(sm, 32, 64);
        if (quad == 0) {
            redmx[wo*64 + ni*16 + sub][wn] = mx;
            redsm[wo*64 + ni*16 + sub][wn] = sm;
        }
    }
    __syncthreads();
    if (tid < 128) {
        float mx = fmaxf(redmx[tid][0], redmx[tid][1]);
        float sm = redsm[tid][0] + redsm[tid][1];
        size_t po = ((size_t)b*16 + nt)*1024 + ot*128 + tid;
        pmax[po] = mx; psum[po] = sm;
    }
}

// ---------------- K6b7: fused [blocks 0..127]: g-reduce; [128..255]: feature branch ----------------
__global__ __launch_bounds__(256) void k6b7_fused(const float* __restrict__ pmax,
                                                  const float* __restrict__ psum,
                                                  float* __restrict__ g,
                                                  const float* __restrict__ x,
                                                  const float* __restrict__ W3,
                                                  const float* __restrict__ W4,
                                                  float* __restrict__ fg) {
    __shared__ float rmx[16*256];
    __shared__ float rsm[16*256];
    int tid = threadIdx.x;
    if (blockIdx.x < 128) {
        int t = blockIdx.x * 256 + tid;
        int b = t >> 10, o = t & 1023;
        float mx = -FINF, sm = 0.0f;
        for (int i = 0; i < 16; ++i) {
            mx = fmaxf(mx, pmax[((size_t)b*16 + i)*1024 + o]);
            sm += psum[((size_t)b*16 + i)*1024 + o];
        }
        g[(size_t)b*2048 + o] = mx;
        g[(size_t)b*2048 + 1024 + o] = sm * (1.0f/2048.0f);
        return;
    }
    int idx = blockIdx.x - 128;
    int og = idx & 3, b = idx >> 2;
    int o0 = og * 16;
    float mx[16], sm[16];
#pragma unroll
    for (int i = 0; i < 16; ++i) { mx[i] = -FINF; sm[i] = 0.0f; }
    for (int n = tid; n < N_; n += 256) {
        const float* xr = x + ((size_t)b*N_ + n)*6 + 3;
        float f0 = xr[0], f1 = xr[1], f2 = xr[2];
        float h1[32];
#pragma unroll
        for (int j = 0; j < 32; ++j) {
            float s = W3[j*3]*f0 + W3[j*3+1]*f1 + W3[j*3+2]*f2;
            h1[j] = lrelu(s);
        }
#pragma unroll
        for (int oi = 0; oi < 16; ++oi) {
            float s = 0.0f;
#pragma unroll
            for (int j = 0; j < 32; ++j) s = fmaf(W4[(o0+oi)*32 + j], h1[j], s);
            s = lrelu(s);
            mx[oi] = fmaxf(mx[oi], s); sm[oi] += s;
        }
    }
#pragma unroll
    for (int oi = 0; oi < 16; ++oi) { rmx[oi*256 + tid] = mx[oi]; rsm[oi*256 + tid] = sm[oi]; }
    __syncthreads();
    for (int s = 128; s > 0; s >>= 1) {
        if (tid < s) {
#pragma unroll
            for (int oi = 0; oi < 16; ++oi) {
                rmx[oi*256 + tid] = fmaxf(rmx[oi*256 + tid], rmx[oi*256 + tid + s]);
                rsm[oi*256 + tid] += rsm[oi*256 + tid + s];
            }
        }
        __syncthreads();
    }
    if (tid < 16) {
        fg[(size_t)b*128 + o0 + tid]      = rmx[tid*256];
        fg[(size_t)b*128 + 64 + o0 + tid] = rsm[tid*256] * (1.0f/2048.0f);
    }
}

// ---------------- K8: head MLP 2176 -> 128 -> 64 -> 40 ----------------
__global__ __launch_bounds__(128) void k8_head(const float* __restrict__ g,
                                               const float* __restrict__ fg,
                                               const float* __restrict__ L1w,
                                               const float* __restrict__ L2w,
                                               const float* __restrict__ L2b,
                                               const float* __restrict__ L3w,
                                               const float* __restrict__ L3b,
                                               float* __restrict__ out) {
    __shared__ float sz[2176];
    __shared__ float s1[128];
    __shared__ float s2[64];
    int b = blockIdx.x, tid = threadIdx.x;
    for (int c = tid; c < 2048; c += 128) sz[c] = g[(size_t)b*2048 + c];
    if (tid < 128) sz[2048 + tid] = fg[(size_t)b*128 + tid];
    __syncthreads();
    {
        float a = 0.0f;
        const float* w = L1w + (size_t)tid * 2176;
        for (int c = 0; c < 2176; ++c) a = fmaf(w[c], sz[c], a);
        s1[tid] = lrelu(a);
    }
    __syncthreads();
    if (tid < 64) {
        float a = L2b[tid];
        for (int c = 0; c < 128; ++c) a = fmaf(L2w[tid*128 + c], s1[c], a);
        s2[tid] = lrelu(a);
    }
    __syncthreads();
    if (tid < 40) {
        float a = L3b[tid];
        for (int c = 0; c < 64; ++c) a = fmaf(L3w[tid*64 + c], s2[c], a);
        out[(size_t)b*40 + tid] = a;
    }
}

// ---------------- launcher ----------------
extern "C" void kernel_launch(void* const* d_in, const int* in_sizes, int n_in,
                              void* d_out, int out_size, void* d_ws, size_t ws_size,
                              hipStream_t stream) {
    const float* x   = (const float*)d_in[0];
    const float* W1  = (const float*)d_in[1];
    const float* W2  = (const float*)d_in[2];
    const float* W5  = (const float*)d_in[3];
    const float* W3  = (const float*)d_in[4];
    const float* W4  = (const float*)d_in[5];
    const float* L1w = (const float*)d_in[6];
    const float* L2w = (const float*)d_in[7];
    const float* L2b = (const float*)d_in[8];
    const float* L3w = (const float*)d_in[9];
    const float* L3b = (const float*)d_in[10];
    float* out = (float*)d_out;

    char* ws = (char*)d_ws;
    float* x1   = (float*)(ws + OFF_X1);
    float* x2   = (float*)(ws + OFF_X2);
    float* sq1  = (float*)(ws + OFF_SQ1);
    int*   idx1 = (int*)  (ws + OFF_IDX1);
    int*   idx2 = (int*)  (ws + OFF_IDX2);
    float* pmax = (float*)(ws + OFF_PMAX);
    float* psum = (float*)(ws + OFF_PSUM);
    float* g    = (float*)(ws + OFF_G);
    float* fg   = (float*)(ws + OFF_FG);
    float* dist = (float*)(ws + OFF_DIST);
    float* P    = (float*)(ws + OFF_P);
    float* Q    = (float*)(ws + OFF_Q);
    unsigned short* Xhi = (unsigned short*)(ws + OFF_XHI);
    unsigned short* Xlo = (unsigned short*)(ws + OFF_XLO);
    unsigned short* Whi = (unsigned short*)(ws + OFF_WHI);
    unsigned short* Wlo = (unsigned short*)(ws + OFF_WLO);

    size_t distBytes = (size_t)N_ * N_ * 4;
    size_t availB = (ws_size > OFF_DIST) ? (ws_size - OFF_DIST) : 0;
    int maxcb = (int)(availB / distBytes);
    int cb = 4;
    while (cb * 2 <= maxcb && cb * 2 <= 32) cb <<= 1;

    k1_knn_pos<<<16384, 256, 0, stream>>>(x, idx1);
    k2_conv1<<<16384, 256, 0, stream>>>(x, idx1, W1, x1, sq1);
    for (int b0 = 0; b0 < 32; b0 += cb) {
        k3_dist<<<dim3(136, cb), 256, 0, stream>>>(x1, sq1, dist, b0);
        k4_topk<<<cb * 512, 256, 0, stream>>>(dist, idx2, b0);
    }
    k5pre_pq<<<640, 256, 0, stream>>>(x1, W2, P, Q, W5, Whi, Wlo);
    k5b_max<<<16384, 256, 0, stream>>>(P, Q, idx2, x1, x2, Xhi, Xlo);
    k6a_mfma<<<dim3(128, 32), 256, 0, stream>>>(Xhi, Xlo, Whi, Wlo, pmax, psum);
    k6b7_fused<<<256, 256, 0, stream>>>(pmax, psum, g, x, W3, W4, fg);
    k8_head<<<32, 128, 0, stream>>>(g, fg, L1w, L2w, L2b, L3w, L3b, out);
}

// Round 10
// 800.236 us; speedup vs baseline: 1.1476x; 1.0601x over previous
//
#include <hip/hip_runtime.h>
#include <math.h>

#define B_ 32
#define N_ 2048
#define KNN 20
#define FINF 3.402823466e38f
#define SCAP 192

typedef __attribute__((ext_vector_type(8))) short short8;
typedef __attribute__((ext_vector_type(4))) float f32x4;

// ---------------- workspace layout (byte offsets) ----------------
#define OFF_X1   ((size_t)0)                                  // B*N*64 f32
#define OFF_X2   (OFF_X1 + (size_t)B_*N_*64*4)                // B*N*64 f32
#define OFF_SQ1  (OFF_X2 + (size_t)B_*N_*64*4)                // B*N f32
#define OFF_IDX1 (OFF_SQ1 + (size_t)B_*N_*4)                  // region kept for Whi/Wlo (idx1 itself no longer materialized)
#define OFF_IDX2 (OFF_IDX1 + (size_t)B_*N_*KNN*4)             // B*N*20 i32
#define OFF_PMAX (OFF_IDX2 + (size_t)B_*N_*KNN*4)             // B*16*1024 f32
#define OFF_PSUM (OFF_PMAX + (size_t)B_*16*1024*4)            // B*16*1024 f32
#define OFF_G    (OFF_PSUM + (size_t)B_*16*1024*4)            // B*2048 f32
#define OFF_FG   (OFF_G + (size_t)B_*2048*4)                  // B*128 f32
#define OFF_DIST (OFF_FG + (size_t)B_*128*4)                  // >=4*N*N f32 = 67.1MB (chunk)
// Overlays of the dist region (sequential lifetimes):
//   after all k4s: P (16.78M), Q (16.78M)   [k5pre writes, k5b reads]
//   after k5pre:   XHI (16.78M), XLO (16.78M)  [k5b writes; disjoint from P/Q]
#define OFF_P    OFF_DIST
#define OFF_Q    (OFF_P   + (size_t)B_*N_*64*4)
#define OFF_XHI  (OFF_Q   + (size_t)B_*N_*64*4)
#define OFF_XLO  (OFF_XHI + (size_t)B_*N_*128*2)
// W5 hi/lo live in the dead idx1 region (0.52MB of 5.2MB):
#define OFF_WHI  OFF_IDX1
#define OFF_WLO  (OFF_WHI + (size_t)1024*128*2)

__device__ __forceinline__ float lrelu(float x) { return x >= 0.0f ? x : 0.2f * x; }

__device__ __forceinline__ void bf16split(float a, unsigned short& hi, unsigned short& lo) {
    unsigned u = __float_as_uint(a);
    unsigned r16 = (u + 0x7fffu + ((u >> 16) & 1u)) >> 16;
    hi = (unsigned short)r16;
    float l = a - __uint_as_float(r16 << 16);
    unsigned ul = __float_as_uint(l);
    lo = (unsigned short)((ul + 0x7fffu + ((ul >> 16) & 1u)) >> 16);
}

// ---------------- exact slow-path top-20 (fallback; writes out20[]) ----------------
template<class F>
__device__ __forceinline__ void wave_top20_slow(const float (&v)[32], int lane, int* out20, F idxf) {
    unsigned alive = 0xffffffffu;
    for (int sel = 0; sel < 20; ++sel) {
        float bv = -FINF;
        int bm = 0x7fffffff;
#pragma unroll
        for (int j = 0; j < 32; ++j) {
            bool a = (alive >> j) & 1u;
            bool better = a && (v[j] > bv);
            bv = better ? v[j] : bv;
            bm = better ? idxf(j) : bm;
        }
#pragma unroll
        for (int off = 32; off; off >>= 1) {
            float ov = __shfl_xor(bv, off, 64);
            int   om = __shfl_xor(bm, off, 64);
            bool take = (ov > bv) || (ov == bv && om < bm);
            bv = take ? ov : bv;
            bm = take ? om : bm;
        }
        if (lane == 0) out20[sel] = bm;
#pragma unroll
        for (int j = 0; j < 32; ++j)
            if (idxf(j) == bm) alive &= ~(1u << j);
    }
}

// ---------------- fast exact top-20: prefilter + compact + bitonic; writes out20[] ----------------
// t_hat = 20th largest of the 64 lane-maxima => >=20 elements >= t_hat and the exact
// top-20 all >= t20 >= t_hat, so survivors contain the exact set.
template<class F>
__device__ __forceinline__ void wave_top20_fast(const float (&v)[32], int lane,
                                                float* sval, int* sidx, int* out20, F idxf) {
    float lm = v[0];
#pragma unroll
    for (int j = 1; j < 32; ++j) lm = fmaxf(lm, v[j]);
    float s = lm;
#pragma unroll
    for (int k = 2; k <= 64; k <<= 1) {
#pragma unroll
        for (int j2 = k >> 1; j2 > 0; j2 >>= 1) {
            float o = __shfl_xor(s, j2, 64);
            bool up = ((lane & k) == 0);
            bool high = ((lane & j2) != 0);
            s = (high == up) ? fmaxf(s, o) : fminf(s, o);
        }
    }
    float that = __shfl(s, 44, 64);   // 20th largest lane-max
    int cnt = 0;
    unsigned long long below = (lane == 63) ? 0xffffffffffffffffull >> 1
                                            : ((1ull << lane) - 1ull);
#pragma unroll
    for (int j = 0; j < 32; ++j) {
        bool p = (v[j] >= that);
        unsigned long long mk = __ballot(p);
        if (p) {
            int slot = cnt + (int)__popcll(mk & below);
            if (slot < SCAP) { sval[slot] = v[j]; sidx[slot] = idxf(j); }
        }
        cnt += (int)__popcll(mk);
    }
    int S = cnt;
    if (S > SCAP) {
        wave_top20_slow(v, lane, out20, idxf);
        return;
    }
    if (S <= 64) {
        bool ok = lane < S;
        float cv = ok ? sval[lane] : -FINF;
        int   cm = ok ? sidx[lane] : 0x7fffffff;
#pragma unroll
        for (int k = 2; k <= 64; k <<= 1) {
#pragma unroll
            for (int j2 = k >> 1; j2 > 0; j2 >>= 1) {
                float ov = __shfl_xor(cv, j2, 64);
                int   om = __shfl_xor(cm, j2, 64);
                bool up = ((lane & k) == 0);
                bool high = ((lane & j2) != 0);
                bool cur_first = (cv > ov) || (cv == ov && cm < om);
                bool take = (high == up) ? cur_first : !cur_first;
                cv = take ? ov : cv;
                cm = take ? om : cm;
            }
        }
        if (lane < 20) out20[lane] = cm;
    } else {
        float cv[3]; int cm[3]; unsigned alive = 0;
#pragma unroll
        for (int r = 0; r < 3; ++r) {
            int i = r * 64 + lane;
            bool ok = i < S;
            float vv = sval[i];
            int   mm = sidx[i];
            cv[r] = ok ? vv : -FINF;
            cm[r] = ok ? mm : 0x7fffffff;
            if (ok) alive |= 1u << r;
        }
        for (int sel = 0; sel < 20; ++sel) {
            float bv = -FINF; int bm = 0x7fffffff;
#pragma unroll
            for (int r = 0; r < 3; ++r) {
                bool a = (alive >> r) & 1u;
                bool better = a && (cv[r] > bv || (cv[r] == bv && cm[r] < bm));
                bv = better ? cv[r] : bv;
                bm = better ? cm[r] : bm;
            }
#pragma unroll
            for (int off = 32; off; off >>= 1) {
                float ov = __shfl_xor(bv, off, 64);
                int   om = __shfl_xor(bm, off, 64);
                bool take = (ov > bv) || (ov == bv && om < bm);
                bv = take ? ov : bv;
                bm = take ? om : bm;
            }
            if (lane == 0) out20[sel] = bm;
#pragma unroll
            for (int r = 0; r < 3; ++r)
                if (cm[r] == bm) alive &= ~(1u << r);
        }
    }
}

// ---------------- K12: fused kNN(3-d) + edgeconv1 (W1: 64x6) + sq ----------------
// Phase 1 (selection): lane = candidate slot, positions staged in LDS
//   (stride 3 floats -> 2 lanes/bank = free). Top-20 written to LDS sOut.
// Phase 2 (conv): lane = output channel o; neighbors read from sP via
//   wave-uniform broadcasts; x1/sq1 written directly. idx1 never hits global.
__global__ __launch_bounds__(256) void k12_knn_conv1(const float* __restrict__ x,
                                                     const float* __restrict__ W1,
                                                     float* __restrict__ x1,
                                                     float* __restrict__ sq1) {
    __shared__ float sP[N_ * 3];          // 24 KB
    __shared__ float sval[4][SCAP];
    __shared__ int   sidx[4][SCAP];
    __shared__ int   sOut[4][20];
    int tid = threadIdx.x;
    int wid = tid >> 6, lane = tid & 63;
    int row = blockIdx.x * 4 + wid;       // 4 rows/block, always same batch (2048 % 4 == 0)
    int b = row >> 11, n = row & 2047;
    const float* xb = x + (size_t)b * N_ * 6;
    for (int m = tid; m < N_; m += 256) {
        float4 f = *(const float4*)(xb + m * 6);
        sP[m*3+0] = f.x; sP[m*3+1] = f.y; sP[m*3+2] = f.z;
    }
    __syncthreads();
    float cx = sP[n*3+0], cy = sP[n*3+1], cz = sP[n*3+2];   // wave-uniform
    float sqn = cx*cx + cy*cy + cz*cz;
    float v[32];
#pragma unroll
    for (int j = 0; j < 32; ++j) {
        int m = lane + (j << 6);
        float mx_ = sP[m*3+0], my = sP[m*3+1], mz = sP[m*3+2];
        float inner = cx*mx_ + cy*my + cz*mz;
        float sqm = mx_*mx_ + my*my + mz*mz;
        v[j] = 2.0f*inner - sqn - sqm;
    }
    wave_top20_fast(v, lane, sval[wid], sidx[wid], sOut[wid],
                    [lane](int j) { return lane + (j << 6); });
    // ---- phase 2: edgeconv1, lane = o ----
    int o = lane;
    float w0 = W1[o*6+0], w1 = W1[o*6+1], w2 = W1[o*6+2];
    float w3 = W1[o*6+3], w4 = W1[o*6+4], w5 = W1[o*6+5];
    float base = w3*cx + w4*cy + w5*cz;
    float mx = -FINF;
#pragma unroll
    for (int k = 0; k < KNN; ++k) {
        int m = sOut[wid][k];             // wave-uniform LDS read
        float dx = sP[m*3+0]-cx, dy = sP[m*3+1]-cy, dz = sP[m*3+2]-cz;
        float s = base + w0*dx + w1*dy + w2*dz;
        mx = fmaxf(mx, lrelu(s));
    }
    x1[(size_t)row*64 + o] = mx;
    float sq = mx*mx;
#pragma unroll
    for (int off = 32; off; off >>= 1) sq += __shfl_xor(sq, off, 64);
    if (o == 0) sq1[row] = sq;
}

// ---------------- K3: neg-dist Gram GEMM (symmetric triangle), chunk of batches ----------------
__global__ __launch_bounds__(256) void k3_dist(const float* __restrict__ x1,
                                               const float* __restrict__ sq1,
                                               float* __restrict__ dist, int b0) {
    __shared__ float sA[32][128];
    __shared__ float sB[32][128];
    int t = blockIdx.x;
    int I = (int)((sqrtf(8.0f*t + 1.0f) - 1.0f) * 0.5f);
    while ((I+1)*(I+2)/2 <= t) ++I;
    while (I*(I+1)/2 > t) --I;
    int J = t - I*(I+1)/2;
    int b = b0 + blockIdx.y;
    const float* Xb  = x1  + (size_t)b * N_ * 64;
    const float* sqb = sq1 + (size_t)b * N_;
    float* Db = dist + (size_t)blockIdx.y * N_ * N_;
    int i0 = I*128, j0 = J*128;
    int tid = threadIdx.x;
    float acc[8][8] = {};
    for (int kt = 0; kt < 64; kt += 32) {
#pragma unroll
        for (int l = 0; l < 4; ++l) {
            int v = l*256 + tid;
            int i = v >> 3, cg = (v & 7) << 2;
            float4 fa = *(const float4*)(Xb + (size_t)(i0+i)*64 + kt + cg);
            sA[cg+0][i] = fa.x; sA[cg+1][i] = fa.y; sA[cg+2][i] = fa.z; sA[cg+3][i] = fa.w;
            float4 fb = *(const float4*)(Xb + (size_t)(j0+i)*64 + kt + cg);
            sB[cg+0][i] = fb.x; sB[cg+1][i] = fb.y; sB[cg+2][i] = fb.z; sB[cg+3][i] = fb.w;
        }
        __syncthreads();
        int ti = (tid & 15) * 8, tj = (tid >> 4) * 8;
#pragma unroll 4
        for (int c = 0; c < 32; ++c) {
            float a[8], w[8];
            *(float4*)&a[0] = *(const float4*)&sA[c][ti];
            *(float4*)&a[4] = *(const float4*)&sA[c][ti+4];
            *(float4*)&w[0] = *(const float4*)&sB[c][tj];
            *(float4*)&w[4] = *(const float4*)&sB[c][tj+4];
#pragma unroll
            for (int ii = 0; ii < 8; ++ii)
#pragma unroll
                for (int jj = 0; jj < 8; ++jj)
                    acc[ii][jj] = fmaf(a[ii], w[jj], acc[ii][jj]);
        }
        __syncthreads();
    }
    int ti = (tid & 15) * 8, tj = (tid >> 4) * 8;
    float sqi[8], sqj[8];
#pragma unroll
    for (int ii = 0; ii < 8; ++ii) sqi[ii] = sqb[i0 + ti + ii];
#pragma unroll
    for (int jj = 0; jj < 8; ++jj) sqj[jj] = sqb[j0 + tj + jj];
#pragma unroll
    for (int ii = 0; ii < 8; ++ii) {
        float ov[8];
#pragma unroll
        for (int jj = 0; jj < 8; ++jj) ov[jj] = 2.0f*acc[ii][jj] - sqi[ii] - sqj[jj];
        float4* p = (float4*)(Db + (size_t)(i0+ti+ii)*N_ + j0 + tj);
        p[0] = *(float4*)&ov[0]; p[1] = *(float4*)&ov[4];
    }
    if (I != J) {
#pragma unroll
        for (int jj = 0; jj < 8; ++jj) {
            float ov[8];
#pragma unroll
            for (int ii = 0; ii < 8; ++ii) ov[ii] = 2.0f*acc[ii][jj] - sqi[ii] - sqj[jj];
            float4* p = (float4*)(Db + (size_t)(j0+tj+jj)*N_ + i0 + ti);
            p[0] = *(float4*)&ov[0]; p[1] = *(float4*)&ov[4];
        }
    }
}

// ---------------- K4: top-20 of materialized dist rows (float4 loads) ----------------
__global__ __launch_bounds__(256) void k4_topk(const float* __restrict__ dist,
                                               int* __restrict__ idx2, int b0) {
    __shared__ float sval[4][SCAP];
    __shared__ int   sidx[4][SCAP];
    __shared__ int   sOut[4][20];
    int wid = threadIdx.x >> 6, lane = threadIdx.x & 63;
    int lrow = blockIdx.x * 4 + wid;
    int lb = lrow >> 11, n = lrow & 2047;
    const float4* Dr4 = (const float4*)(dist + (size_t)lb * N_ * N_ + (size_t)n * N_);
    float v[32];
#pragma unroll
    for (int j4 = 0; j4 < 8; ++j4) {
        float4 f = Dr4[(j4 << 6) + lane];
        v[j4*4+0] = f.x; v[j4*4+1] = f.y; v[j4*4+2] = f.z; v[j4*4+3] = f.w;
    }
    wave_top20_fast(v, lane, sval[wid], sidx[wid], sOut[wid],
                    [lane](int j) { return (lane << 2) + ((j >> 2) << 8) + (j & 3); });
    int row = (b0 + lb) * N_ + n;
    if (lane < 20) idx2[(size_t)row*KNN + lane] = sOut[wid][lane];
}

// ---------------- K5pre: P = x1 @ Wd^T, Q = x1 @ (Wc-Wd)^T; blocks >=512 split W5 ----------------
__global__ __launch_bounds__(256) void k5pre_pq(const float* __restrict__ x1,
                                                const float* __restrict__ W2,
                                                float* __restrict__ P,
                                                float* __restrict__ Q,
                                                const float* __restrict__ W5,
                                                unsigned short* __restrict__ Whi,
                                                unsigned short* __restrict__ Wlo) {
    if (blockIdx.x >= 512) {
        int e = (blockIdx.x - 512) * 256 + threadIdx.x;
        int r = e >> 5, c4 = (e & 31) << 2;
        float4 v = *(const float4*)(W5 + (size_t)r*128 + c4);
        float a[4] = {v.x, v.y, v.z, v.w};
        unsigned short hh[4], ll[4];
#pragma unroll
        for (int i = 0; i < 4; ++i) bf16split(a[i], hh[i], ll[i]);
        size_t doff = (size_t)r*128 + c4;
        *(uint2*)(Whi + doff) = make_uint2((unsigned)hh[0] | ((unsigned)hh[1] << 16),
                                           (unsigned)hh[2] | ((unsigned)hh[3] << 16));
        *(uint2*)(Wlo + doff) = make_uint2((unsigned)ll[0] | ((unsigned)ll[1] << 16),
                                           (unsigned)ll[2] | ((unsigned)ll[3] << 16));
        return;
    }
    int w = threadIdx.x >> 6, o = threadIdx.x & 63;
    float wd[64], wc[64];
    const float* wsrc = W2 + (size_t)o * 128;
#pragma unroll
    for (int j = 0; j < 16; ++j) {
        float4 d = *(const float4*)(wsrc + j*4);
        float4 c = *(const float4*)(wsrc + 64 + j*4);
        wd[j*4+0] = d.x; wd[j*4+1] = d.y; wd[j*4+2] = d.z; wd[j*4+3] = d.w;
        wc[j*4+0] = c.x - d.x; wc[j*4+1] = c.y - d.y; wc[j*4+2] = c.z - d.z; wc[j*4+3] = c.w - d.w;
    }
    int row0 = (blockIdx.x * 4 + w) * 32;
    for (int r = 0; r < 32; ++r) {
        const float* xr = x1 + (size_t)(row0 + r) * 64;
        float p = 0.0f, q = 0.0f;
#pragma unroll
        for (int j = 0; j < 16; ++j) {
            float4 xc = *(const float4*)(xr + j*4);   // wave-uniform
            p = fmaf(wd[j*4+0], xc.x, p); q = fmaf(wc[j*4+0], xc.x, q);
            p = fmaf(wd[j*4+1], xc.y, p); q = fmaf(wc[j*4+1], xc.y, q);
            p = fmaf(wd[j*4+2], xc.z, p); q = fmaf(wc[j*4+2], xc.z, q);
            p = fmaf(wd[j*4+3], xc.w, p); q = fmaf(wc[j*4+3], xc.w, q);
        }
        P[(size_t)(row0 + r) * 64 + o] = p;
        Q[(size_t)(row0 + r) * 64 + o] = q;
    }
}

// ---------------- K5b: x2 = max_k lrelu(P[m_k]+Q[n]); fused bf16 hi/lo split of [x1|x2] ----------------
__global__ __launch_bounds__(256) void k5b_max(const float* __restrict__ P,
                                               const float* __restrict__ Q,
                                               const int* __restrict__ idx2,
                                               const float* __restrict__ x1,
                                               float* __restrict__ x2,
                                               unsigned short* __restrict__ Xhi,
                                               unsigned short* __restrict__ Xlo) {
    int w = threadIdx.x >> 6, lane = threadIdx.x & 63;
    int row = blockIdx.x * 4 + w;
    int b = row >> 11;
    float q = Q[(size_t)row * 64 + lane];
    const int* id = idx2 + (size_t)row * KNN;
    const float* Pb = P + ((size_t)b << 11) * 64;
    int midx[KNN];
#pragma unroll
    for (int k = 0; k < KNN; ++k) midx[k] = id[k];
    float mx = -FINF;
#pragma unroll
    for (int k = 0; k < KNN; ++k) {
        float p = Pb[(size_t)midx[k] * 64 + lane];
        mx = fmaxf(mx, lrelu(p + q));
    }
    x2[(size_t)row * 64 + lane] = mx;
    float x1v = x1[(size_t)row * 64 + lane];
    unsigned short h0, l0, h1, l1;
    bf16split(x1v, h0, l0);
    bf16split(mx,  h1, l1);
    size_t base = (size_t)row * 128 + lane;
    Xhi[base] = h0;      Xlo[base] = l0;
    Xhi[base + 64] = h1; Xlo[base + 64] = l1;
}

// ---------------- K6a (MFMA): h = lrelu(X @ W5^T) split-bf16, fused max/sum pool ----------------
__global__ __launch_bounds__(256) void k6a_mfma(const unsigned short* __restrict__ Xhi,
                                                const unsigned short* __restrict__ Xlo,
                                                const unsigned short* __restrict__ Whi,
                                                const unsigned short* __restrict__ Wlo,
                                                float* __restrict__ pmax,
                                                float* __restrict__ psum) {
    __shared__ unsigned short sT[4][128*32];   // Xh, Xl, Wh, Wl (8KB each)
    __shared__ float redmx[128][2], redsm[128][2];
    int tid = threadIdx.x;
    int nt = blockIdx.x >> 3, ot = blockIdx.x & 7, b = blockIdx.y;
    int wid = tid >> 6, lane = tid & 63;
    int wn = wid & 1, wo = wid >> 1;
    int sub = lane & 15, quad = lane >> 4;
    const unsigned short* gp[4];
    gp[0] = Xhi + (size_t)(b*2048 + nt*128) * 128;
    gp[1] = Xlo + (size_t)(b*2048 + nt*128) * 128;
    gp[2] = Whi + (size_t)(ot*128) * 128;
    gp[3] = Wlo + (size_t)(ot*128) * 128;
    f32x4 acc[4][4];
#pragma unroll
    for (int i = 0; i < 4; ++i)
#pragma unroll
        for (int j = 0; j < 4; ++j) acc[i][j] = (f32x4)0.0f;
    for (int kt = 0; kt < 4; ++kt) {
        int k0 = kt * 32;
        __syncthreads();
#pragma unroll
        for (int it = 0; it < 8; ++it) {
            int task = it*256 + tid;
            int tile = task >> 9, rem = task & 511;
            int row = rem >> 2, ch = rem & 3;
            uint4 d = *(const uint4*)(gp[tile] + (size_t)row*128 + k0 + ch*8);
            *(uint4*)(&sT[tile][row*32 + ch*8]) = d;
        }
        __syncthreads();
        short8 ah[4], al[4], bh[4], bl[4];
#pragma unroll
        for (int mi = 0; mi < 4; ++mi) {
            int r = wn*64 + mi*16 + sub;
            ah[mi] = *(const short8*)(&sT[0][r*32 + quad*8]);
            al[mi] = *(const short8*)(&sT[1][r*32 + quad*8]);
        }
#pragma unroll
        for (int ni = 0; ni < 4; ++ni) {
            int r = wo*64 + ni*16 + sub;
            bh[ni] = *(const short8*)(&sT[2][r*32 + quad*8]);
            bl[ni] = *(const short8*)(&sT[3][r*32 + quad*8]);
        }
#pragma unroll
        for (int mi = 0; mi < 4; ++mi)
#pragma unroll
            for (int ni = 0; ni < 4; ++ni) {
                acc[mi][ni] = __builtin_amdgcn_mfma_f32_16x16x32_bf16(ah[mi], bh[ni], acc[mi][ni], 0, 0, 0);
                acc[mi][ni] = __builtin_amdgcn_mfma_f32_16x16x32_bf16(ah[mi], bl[ni], acc[mi][ni], 0, 0, 0);
                acc[mi][ni] = __builtin_amdgcn_mfma_f32_16x16x32_bf16(al[mi], bh[ni], acc[mi][ni], 0, 0, 0);
            }
    }
#pragma unroll
    for (int ni = 0; ni < 4; ++ni) {
        float mx = -FINF, sm = 0.0f;
#pragma unroll
        for (int mi = 0; mi < 4; ++mi)
#pragma unroll
            for (int r = 0; r < 4; ++r) {
                float v = lrelu(acc[mi][ni][r]);
                mx = fmaxf(mx, v); sm += v;
            }
        mx = fmaxf(mx, __shfl_xor(mx, 16, 64));
        mx = fmaxf(mx, __shfl_xor(mx, 32, 64));
        sm += __shfl_xor(sm, 16, 64);
        sm += __shfl_xor(sm, 32, 64);
        if (quad == 0) {
            redmx[wo*64 + ni*16 + sub][wn] = mx;
            redsm[wo*64 + ni*16 + sub][wn] = sm;
        }
    }
    __syncthreads();
    if (tid < 128) {
        float mx = fmaxf(redmx[tid][0], redmx[tid][1]);
        float sm = redsm[tid][0] + redsm[tid][1];
        size_t po = ((size_t)b*16 + nt)*1024 + ot*128 + tid;
        pmax[po] = mx; psum[po] = sm;
    }
}

// ---------------- K6b7: fused [blocks 0..127]: g-reduce; [128..255]: feature branch ----------------
__global__ __launch_bounds__(256) void k6b7_fused(const float* __restrict__ pmax,
                                                  const float* __restrict__ psum,
                                                  float* __restrict__ g,
                                                  const float* __restrict__ x,
                                                  const float* __restrict__ W3,
                                                  const float* __restrict__ W4,
                                                  float* __restrict__ fg) {
    __shared__ float rmx[16*256];
    __shared__ float rsm[16*256];
    int tid = threadIdx.x;
    if (blockIdx.x < 128) {
        int t = blockIdx.x * 256 + tid;
        int b = t >> 10, o = t & 1023;
        float mx = -FINF, sm = 0.0f;
        for (int i = 0; i < 16; ++i) {
            mx = fmaxf(mx, pmax[((size_t)b*16 + i)*1024 + o]);
            sm += psum[((size_t)b*16 + i)*1024 + o];
        }
        g[(size_t)b*2048 + o] = mx;
        g[(size_t)b*2048 + 1024 + o] = sm * (1.0f/2048.0f);
        return;
    }
    int idx = blockIdx.x - 128;
    int og = idx & 3, b = idx >> 2;
    int o0 = og * 16;
    float mx[16], sm[16];
#pragma unroll
    for (int i = 0; i < 16; ++i) { mx[i] = -FINF; sm[i] = 0.0f; }
    for (int n = tid; n < N_; n += 256) {
        const float* xr = x + ((size_t)b*N_ + n)*6 + 3;
        float f0 = xr[0], f1 = xr[1], f2 = xr[2];
        float h1[32];
#pragma unroll
        for (int j = 0; j < 32; ++j) {
            float s = W3[j*3]*f0 + W3[j*3+1]*f1 + W3[j*3+2]*f2;
            h1[j] = lrelu(s);
        }
#pragma unroll
        for (int oi = 0; oi < 16; ++oi) {
            float s = 0.0f;
#pragma unroll
            for (int j = 0; j < 32; ++j) s = fmaf(W4[(o0+oi)*32 + j], h1[j], s);
            s = lrelu(s);
            mx[oi] = fmaxf(mx[oi], s); sm[oi] += s;
        }
    }
#pragma unroll
    for (int oi = 0; oi < 16; ++oi) { rmx[oi*256 + tid] = mx[oi]; rsm[oi*256 + tid] = sm[oi]; }
    __syncthreads();
    for (int s = 128; s > 0; s >>= 1) {
        if (tid < s) {
#pragma unroll
            for (int oi = 0; oi < 16; ++oi) {
                rmx[oi*256 + tid] = fmaxf(rmx[oi*256 + tid], rmx[oi*256 + tid + s]);
                rsm[oi*256 + tid] += rsm[oi*256 + tid + s];
            }
        }
        __syncthreads();
    }
    if (tid < 16) {
        fg[(size_t)b*128 + o0 + tid]      = rmx[tid*256];
        fg[(size_t)b*128 + 64 + o0 + tid] = rsm[tid*256] * (1.0f/2048.0f);
    }
}

// ---------------- K8: head MLP 2176 -> 128 -> 64 -> 40 ----------------
__global__ __launch_bounds__(128) void k8_head(const float* __restrict__ g,
                                               const float* __restrict__ fg,
                                               const float* __restrict__ L1w,
                                               const float* __restrict__ L2w,
                                               const float* __restrict__ L2b,
                                               const float* __restrict__ L3w,
                                               const float* __restrict__ L3b,
                                               float* __restrict__ out) {
    __shared__ float sz[2176];
    __shared__ float s1[128];
    __shared__ float s2[64];
    int b = blockIdx.x, tid = threadIdx.x;
    for (int c = tid; c < 2048; c += 128) sz[c] = g[(size_t)b*2048 + c];
    if (tid < 128) sz[2048 + tid] = fg[(size_t)b*128 + tid];
    __syncthreads();
    {
        float a = 0.0f;
        const float* w = L1w + (size_t)tid * 2176;
        for (int c = 0; c < 2176; ++c) a = fmaf(w[c], sz[c], a);
        s1[tid] = lrelu(a);
    }
    __syncthreads();
    if (tid < 64) {
        float a = L2b[tid];
        for (int c = 0; c < 128; ++c) a = fmaf(L2w[tid*128 + c], s1[c], a);
        s2[tid] = lrelu(a);
    }
    __syncthreads();
    if (tid < 40) {
        float a = L3b[tid];
        for (int c = 0; c < 64; ++c) a = fmaf(L3w[tid*64 + c], s2[c], a);
        out[(size_t)b*40 + tid] = a;
    }
}

// ---------------- launcher ----------------
extern "C" void kernel_launch(void* const* d_in, const int* in_sizes, int n_in,
                              void* d_out, int out_size, void* d_ws, size_t ws_size,
                              hipStream_t stream) {
    const float* x   = (const float*)d_in[0];
    const float* W1  = (const float*)d_in[1];
    const float* W2  = (const float*)d_in[2];
    const float* W5  = (const float*)d_in[3];
    const float* W3  = (const float*)d_in[4];
    const float* W4  = (const float*)d_in[5];
    const float* L1w = (const float*)d_in[6];
    const float* L2w = (const float*)d_in[7];
    const float* L2b = (const float*)d_in[8];
    const float* L3w = (const float*)d_in[9];
    const float* L3b = (const float*)d_in[10];
    float* out = (float*)d_out;

    char* ws = (char*)d_ws;
    float* x1   = (float*)(ws + OFF_X1);
    float* x2   = (float*)(ws + OFF_X2);
    float* sq1  = (float*)(ws + OFF_SQ1);
    int*   idx2 = (int*)  (ws + OFF_IDX2);
    float* pmax = (float*)(ws + OFF_PMAX);
    float* psum = (float*)(ws + OFF_PSUM);
    float* g    = (float*)(ws + OFF_G);
    float* fg   = (float*)(ws + OFF_FG);
    float* dist = (float*)(ws + OFF_DIST);
    float* P    = (float*)(ws + OFF_P);
    float* Q    = (float*)(ws + OFF_Q);
    unsigned short* Xhi = (unsigned short*)(ws + OFF_XHI);
    unsigned short* Xlo = (unsigned short*)(ws + OFF_XLO);
    unsigned short* Whi = (unsigned short*)(ws + OFF_WHI);
    unsigned short* Wlo = (unsigned short*)(ws + OFF_WLO);

    size_t distBytes = (size_t)N_ * N_ * 4;
    size_t availB = (ws_size > OFF_DIST) ? (ws_size - OFF_DIST) : 0;
    int maxcb = (int)(availB / distBytes);
    int cb = 4;
    while (cb * 2 <= maxcb && cb * 2 <= 32) cb <<= 1;

    k12_knn_conv1<<<16384, 256, 0, stream>>>(x, W1, x1, sq1);
    for (int b0 = 0; b0 < 32; b0 += cb) {
        k3_dist<<<dim3(136, cb), 256, 0, stream>>>(x1, sq1, dist, b0);
        k4_topk<<<cb * 512, 256, 0, stream>>>(dist, idx2, b0);
    }
    k5pre_pq<<<640, 256, 0, stream>>>(x1, W2, P, Q, W5, Whi, Wlo);
    k5b_max<<<16384, 256, 0, stream>>>(P, Q, idx2, x1, x2, Xhi, Xlo);
    k6a_mfma<<<dim3(128, 32), 256, 0, stream>>>(Xhi, Xlo, Whi, Wlo, pmax, psum);
    k6b7_fused<<<256, 256, 0, stream>>>(pmax, psum, g, x, W3, W4, fg);
    k8_head<<<32, 128, 0, stream>>>(g, fg, L1w, L2w, L2b, L3w, L3b, out);
}